// Round 1
// baseline (408.206 us; speedup 1.0000x reference)
//
#include <hip/hip_runtime.h>
#include <hip/hip_bf16.h>
#include <climits>

#define B_ 2
#define V_ 4
#define H_ 120
#define W_ 160
#define C_ 96
#define NVOX 200000
#define GRID_ 128
#define NSTEPS 156
#define NRAYS (B_*V_*H_*W_)   // 153600

// ---------------- Kernel A: per-batch component-wise min of coords ----------
__global__ void shift_kernel(const int* __restrict__ coords, int* __restrict__ shifts) {
    __shared__ int smin[B_ * 3];
    int t = threadIdx.x;
    if (t < B_ * 3) smin[t] = INT_MAX;
    __syncthreads();
    int i = blockIdx.x * blockDim.x + t;
    if (i < NVOX) {
        int b = coords[i * 4 + 0];
        atomicMin(&smin[b * 3 + 0], coords[i * 4 + 1]);
        atomicMin(&smin[b * 3 + 1], coords[i * 4 + 2]);
        atomicMin(&smin[b * 3 + 2], coords[i * 4 + 3]);
    }
    __syncthreads();
    if (t < B_ * 3 && smin[t] != INT_MAX) atomicMin(&shifts[t], smin[t]);
}

// ---------------- Kernel B: build occupancy grid (last-dup wins -> atomicMax)
__global__ void occ_kernel(const int* __restrict__ coords,
                           const int* __restrict__ shifts,
                           int* __restrict__ occ) {
    int i = blockIdx.x * blockDim.x + threadIdx.x;
    if (i >= NVOX) return;
    int b = coords[i * 4 + 0];
    int x = coords[i * 4 + 1] - shifts[b * 3 + 0];
    int y = coords[i * 4 + 2] - shifts[b * 3 + 1];
    int z = coords[i * 4 + 3] - shifts[b * 3 + 2];
    int idx = ((b * GRID_ + z) * GRID_ + y) * GRID_ + x;
    atomicMax(&occ[idx], i);
}

// ---------------- Kernel C: ray march, first hit -> tgt ---------------------
__global__ void march_kernel(const float* __restrict__ vm,
                             const float* __restrict__ intr,
                             const int* __restrict__ shifts,
                             const int* __restrict__ occ,
                             int* __restrict__ tgt) {
    int r = blockIdx.x * blockDim.x + threadIdx.x;
    if (r >= NRAYS) return;
    int w = r % W_;
    int h = (r / W_) % H_;
    int v = (r / (W_ * H_)) % V_;
    int b = r / (W_ * H_ * V_);
    const float* M = vm + (size_t)(b * V_ + v) * 16;
    float fx = intr[0], fy = intr[1], cx = intr[2], cy = intr[3];
    float dx = ((float)w + 0.5f - cx) / fx;
    float dy = ((float)h + 0.5f - cy) / fy;
    float R00 = M[0], R01 = M[1], R02 = M[2];
    float R10 = M[4], R11 = M[5], R12 = M[6];
    float R20 = M[8], R21 = M[9], R22 = M[10];
    float t0 = M[3]  - (float)shifts[b * 3 + 0];
    float t1 = M[7]  - (float)shifts[b * 3 + 1];
    float t2 = M[11] - (float)shifts[b * 3 + 2];
    int res = -1;
    for (int s = 0; s < NSTEPS; ++s) {
        float t = 2.0f + 0.5f * (float)s;
        float px = dx * t, py = dy * t, pz = t;
        float pwx = R00 * px + R01 * py + R02 * pz + t0;
        float pwy = R10 * px + R11 * py + R12 * pz + t1;
        float pwz = R20 * px + R21 * py + R22 * pz + t2;
        int ix = (int)floorf(pwx);
        int iy = (int)floorf(pwy);
        int iz = (int)floorf(pwz);
        if (((unsigned)ix < (unsigned)GRID_) & ((unsigned)iy < (unsigned)GRID_) &
            ((unsigned)iz < (unsigned)GRID_)) {
            int id = occ[((b * GRID_ + iz) * GRID_ + iy) * GRID_ + ix];
            if (id >= 0) { res = id; break; }
        }
    }
    tgt[r] = res;
}

// ---------------- Kernel D: wave-per-ray feature scatter-add ----------------
__global__ void scatter_kernel(const float* __restrict__ feats,
                               const int* __restrict__ tgt,
                               float* __restrict__ proj,
                               int* __restrict__ cnt) {
    int gtid = blockIdx.x * blockDim.x + threadIdx.x;
    int ray  = gtid >> 6;
    int lane = threadIdx.x & 63;
    if (ray >= NRAYS) return;
    int t = tgt[ray];
    if (t < 0) return;
    const float* f = feats + (size_t)ray * C_;
    float* p = proj + (size_t)t * C_;
    unsafeAtomicAdd(&p[lane], f[lane]);
    if (lane < C_ - 64) unsafeAtomicAdd(&p[64 + lane], f[64 + lane]);
    if (lane == 0) atomicAdd(&cnt[t], 1);
}

// ---------------- Kernel E: finalize out = proj/(cnt+1e-4), cnt -> float ----
__global__ void finalize_kernel(const int* __restrict__ cnt,
                                float* __restrict__ out,
                                float* __restrict__ cnt_out) {
    int idx = blockIdx.x * blockDim.x + threadIdx.x;
    if (idx < NVOX * C_) {
        int i = idx / C_;
        out[idx] = out[idx] / ((float)cnt[i] + 0.0001f);
    }
    if (idx < NVOX) cnt_out[idx] = (float)cnt[idx];
}

extern "C" void kernel_launch(void* const* d_in, const int* in_sizes, int n_in,
                              void* d_out, int out_size, void* d_ws, size_t ws_size,
                              hipStream_t stream) {
    const float* feats  = (const float*)d_in[0];
    const int*   coords = (const int*)d_in[1];
    const float* vm     = (const float*)d_in[2];
    const float* intr   = (const float*)d_in[3];

    float* out     = (float*)d_out;                  // NVOX*C_ floats
    float* cnt_out = out + (size_t)NVOX * C_;        // NVOX floats

    char* ws = (char*)d_ws;
    int* shifts = (int*)ws;                                    // 256 B slot
    int* cnt    = (int*)(ws + 256);                            // 800,000 B
    int* tgt    = (int*)(ws + 256 + 800000);                   // 614,400 B
    int* occ    = (int*)(ws + 256 + 800000 + 614400);          // 33,554,432 B

    hipMemsetAsync(d_out, 0, (size_t)out_size * sizeof(float), stream);
    hipMemsetAsync(shifts, 0x7F, 256, stream);                 // big positive ints
    hipMemsetAsync(cnt, 0, (size_t)NVOX * sizeof(int), stream);
    hipMemsetAsync(occ, 0xFF, (size_t)B_ * GRID_ * GRID_ * GRID_ * sizeof(int), stream); // -1

    shift_kernel<<<(NVOX + 255) / 256, 256, 0, stream>>>(coords, shifts);
    occ_kernel<<<(NVOX + 255) / 256, 256, 0, stream>>>(coords, shifts, occ);
    march_kernel<<<(NRAYS + 255) / 256, 256, 0, stream>>>(vm, intr, shifts, occ, tgt);
    scatter_kernel<<<(NRAYS * 64 + 255) / 256, 256, 0, stream>>>(feats, tgt, (float*)d_out, cnt);
    finalize_kernel<<<(NVOX * C_ + 255) / 256, 256, 0, stream>>>(cnt, (float*)d_out, cnt_out);
}